// Round 14
// baseline (228.595 us; speedup 1.0000x reference)
//
#include <hip/hip_runtime.h>
#include <math.h>

#define B_   2
#define N_   4096
#define S_   48
#define NPL  32
#define NRAYS (B_*N_)          // 8192
#define NPTS  (NRAYS*S_)       // 393216
#define DELTA_ (2.0f/47.0f)
#define NBLK_FUSED (NPTS/256)  // 1536 (512 thr: 8 waves x 32 pts = 256 pts/block)

// x-pair texel table: entry (plane, y, x) = texels (y,x),(y,x+1), 3ch bf16 each, 16B aligned.
#define ST_XS    65                     // x0 in [0,64]
#define ST_YS    66                     // y in [0,65]
#define ST_PLANE (ST_YS*ST_XS)          // 4290 uint4 entries per plane
#define SETUP_GRID 258                  // poses+weights + minmax + 64 planes x 4 parts

// ---- workspace layout (float offsets) ----
#define OFF_POSES  0                    // 384 (pk layout: [ax,bx,ay,by,az,bz,aw,bw,c0..c3] per plane)
#define OFF_MINMAX 384                  // 2 floats (gmin, gmax)
#define OFF_W1E    512                  // 64*256 bf16 (wave-layout [chunk][lane][8])
#define OFF_W2E    8704                 // 6*512 bf16 (wave-layout)
#define OFF_B2E    10240                // 48 floats
#define OFF_ST     16384                // table: 64*4290 uint4 = 1098240 floats -> ends 1114624
#define OFF_DC     1114624              // depths_c [NPTS]
#define OFF_DF     1507840
#define OFF_SC     1901056
#define OFF_SF     2294272
#define OFF_CC     2687488              // colors_c bf16 [NPTS*32] -> ends 8978944
#define OFF_CF     8978944              // colors_f bf16 -> ends 15270400

typedef __attribute__((ext_vector_type(8))) short short8;
typedef __attribute__((ext_vector_type(4))) float f32x4;
typedef __attribute__((ext_vector_type(2))) float f32x2;

__device__ __forceinline__ float softplus_f(float x) {
    return fmaxf(x, 0.f) + __logf(1.f + __expf(-fabsf(x)));
}
__device__ __forceinline__ float sigmoid_f(float x) {
    return __builtin_amdgcn_rcpf(1.f + __expf(-x));
}
__device__ __forceinline__ unsigned short bf16rne(float x) {
    unsigned u = __float_as_uint(x);
    u += 0x7FFFu + ((u >> 16) & 1u);
    return (unsigned short)(u >> 16);
}
__device__ __forceinline__ unsigned bf16pk(float lo, float hi) {
    return (unsigned)bf16rne(lo) | ((unsigned)bf16rne(hi) << 16);
}
__device__ __forceinline__ float bf2f(unsigned short v) {
    return __uint_as_float(((unsigned)v) << 16);
}
__device__ __forceinline__ float bflo(unsigned u) { return __uint_as_float(u << 16); }
__device__ __forceinline__ float bfhi(unsigned u) { return __uint_as_float(u & 0xffff0000u); }
__device__ __forceinline__ f32x2 unpk2(unsigned u) { return (f32x2){bflo(u), bfhi(u)}; }
// exact n/48 for n < 393216 (n>>4 < 24576: 43691 = ceil(2^17/3))
__device__ __forceinline__ int div48(int pt) {
    return (int)(((unsigned)(pt >> 4) * 43691u) >> 17);
}

__device__ void mul3(const double* a, const double* b, double* o) {
    for (int i = 0; i < 3; i++)
        for (int j = 0; j < 3; j++) {
            double s = 0.0;
            for (int k = 0; k < 3; k++) s += a[i*3+k]*b[k*3+j];
            o[i*3+j] = s;
        }
}

// ---- kernel 0: setup (258 blocks) ----
// bid 0: poses (pk layout) + weight repack; bid 1: depth minmax;
// bid 2..257: plane repack, 4 blocks per plane.
__global__ __launch_bounds__(256) void k_setup(
    float* ws, const float* __restrict__ W1,
    const float* __restrict__ W2, const float* __restrict__ b2,
    const float* __restrict__ planes, const float* __restrict__ noise)
{
    __shared__ unsigned short texs[3][4096];    // 24 KB (repack branch)
    __shared__ float smn[4], smx[4];
    int bid = blockIdx.x;
    int t = threadIdx.x;
    if (bid == 0) {
        // poses (double math, faithful)
        if (t < 32) {
            double y = 1.0 - (t/31.0)*2.0;
            double rr = sqrt(fmax(1.0 - y*y, 0.0));
            double golden = M_PI*(sqrt(5.0) - 1.0);
            double th = golden*(double)t;
            double x = cos(th)*rr, z = sin(th)*rr;
            double phi   = atan2(z, sqrt(x*x + y*y));   // radians treated as degrees (faithful)
            double theta = atan2(y, x);
            double p  = phi/180.0*M_PI;
            double tt = theta/180.0*M_PI;
            double e  = 90.0/180.0*M_PI;
            double cp = cos(p), sp = sin(p), ct = cos(tt), st = sin(tt);
            double ce = cos(e), se = sin(e);
            double Ph[9] = {1,0,0,  0,cp,-sp,  0,sp,cp};
            double Th[9] = {ct,0,-st,  0,1,0,  st,0,ct};
            double Et[9] = {ce,se,0,  -se,ce,0,  0,0,1};
            double M3[9] = {-1,0,0,  0,0,1,  0,1,0};
            double A[9], Bm[9], R[9];
            mul3(Th, Ph, A);
            mul3(Et, A, Bm);
            mul3(M3, Bm, R);
            double radius = -1.307;
            double tv0 = radius*R[2], tv1 = radius*R[5], tv2 = radius*R[8];
            double Rf[9] = {-R[0],R[1],R[2], -R[3],R[4],R[5], -R[6],R[7],R[8]};
            float rowv[3][4];
            for (int j = 0; j < 3; j++) {
                double r0 = Rf[0*3+j], r1 = Rf[1*3+j], r2 = Rf[2*3+j];
                rowv[j][0] = (float)r0;
                rowv[j][1] = (float)r1;
                rowv[j][2] = (float)r2;
                rowv[j][3] = (float)(-(r0*tv0 + r1*tv1 + r2*tv2));
            }
            // pk layout: row0/row1 interleaved by component, then row2
            float* P = ws + OFF_POSES + t*12;
            P[0] = rowv[0][0]; P[1] = rowv[1][0];
            P[2] = rowv[0][1]; P[3] = rowv[1][1];
            P[4] = rowv[0][2]; P[5] = rowv[1][2];
            P[6] = rowv[0][3]; P[7] = rowv[1][3];
            P[8] = rowv[2][0]; P[9] = rowv[2][1]; P[10] = rowv[2][2]; P[11] = rowv[2][3];
        }
        // layer-1 weights, wave layout: o = [chunk=s*4+nt][lane=q*16+n][j]
        unsigned short* w1e = (unsigned short*)(ws + OFF_W1E);
        for (int o = t; o < 64*256; o += 256) {
            int chunk = o >> 9, lane = (o >> 3) & 63, j = o & 7;
            int s = chunk >> 2, nt = chunk & 3, q = lane >> 4, n = lane & 15;
            int nn = nt*16 + n;
            int p = s*4 + q;
            float v = 0.f;
            if (j < 3)      v = W1[(3*p+j)*64 + nn];
            else if (j < 5) v = W1[(96 + 2*p + (j-3))*64 + nn];
            w1e[o] = bf16rne(v);
        }
        // layer-2 weights, wave layout: o = [chunk=nt*2+s2][lane][j]
        unsigned short* w2e = (unsigned short*)(ws + OFF_W2E);
        for (int o = t; o < 6*512; o += 256) {
            int chunk = o >> 9, lane = (o >> 3) & 63, j = o & 7;
            int nt = chunk >> 1, s2 = chunk & 1, q = lane >> 4, n = lane & 15;
            int nn = nt*16 + n;
            int k2 = s2*32 + q*8 + j;
            float v = (nn < 33) ? W2[k2*33 + nn] : 0.f;
            w2e[o] = bf16rne(v);
        }
        for (int idx = t; idx < 48; idx += 256)
            ws[OFF_B2E + idx] = (idx < 33) ? b2[idx] : 0.f;
    } else if (bid == 1) {
        // depth minmax over noise col 0 / col 47
        float mn = 1e30f, mx = -1e30f;
        for (int r = t; r < NRAYS; r += 256) {
            float n0  = noise[(size_t)r*48];
            float n47 = noise[(size_t)r*48 + 47];
            mn = fminf(mn, 0.5f + n0*DELTA_);
            mx = fmaxf(mx, 0.5f + 47.f*DELTA_ + n47*DELTA_);
        }
        for (int off = 32; off > 0; off >>= 1) {
            mn = fminf(mn, __shfl_down(mn, off));
            mx = fmaxf(mx, __shfl_down(mx, off));
        }
        if ((t & 63) == 0) { smn[t >> 6] = mn; smx[t >> 6] = mx; }
        __syncthreads();
        if (t == 0) {
            ws[OFF_MINMAX]     = fminf(fminf(smn[0], smn[1]), fminf(smn[2], smn[3]));
            ws[OFF_MINMAX + 1] = fmaxf(fmaxf(smx[0], smx[1]), fmaxf(smx[2], smx[3]));
        }
    } else {
        // plane-staged x-pair repack: 4 blocks per plane, each writes a quarter.
        int idx = bid - 2;
        int bp = idx >> 2, part = idx & 3;        // plane 0..63, quarter 0..3
        int b = bp >> 5, p = bp & 31;
        const float* base = planes + ((size_t)b*96 + 3*p)*4096;
        for (int i = t; i < 4096; i += 256) {
            texs[0][i] = bf16rne(base[i]);
            texs[1][i] = bf16rne(base[4096 + i]);
            texs[2][i] = bf16rne(base[8192 + i]);
        }
        __syncthreads();
        uint4* qd = (uint4*)(ws + OFF_ST) + (size_t)bp*ST_PLANE;
        int e0 = part*1073, e1 = min(ST_PLANE, e0 + 1073);
        for (int e = e0 + t; e < e1; e += 256) {
            int y = e / ST_XS, x = e - y*ST_XS;   // y in [0,65], x in [0,64]
            int jy = y - 1;
            unsigned a01 = 0, a2 = 0, b01 = 0, b2v = 0;
            if (jy >= 0 && jy <= 63) {
                int jxa = x - 1, jxb = x;
                if (jxa >= 0 && jxa <= 63) {
                    int ti = jy*64 + jxa;
                    a01 = (unsigned)texs[0][ti] | ((unsigned)texs[1][ti] << 16);
                    a2  = (unsigned)texs[2][ti];
                }
                if (jxb <= 63) {
                    int ti = jy*64 + jxb;
                    b01 = (unsigned)texs[0][ti] | ((unsigned)texs[1][ti] << 16);
                    b2v = (unsigned)texs[2][ti];
                }
            }
            qd[e] = make_uint4(a01, a2, b01, b2v);
        }
    }
}

// ---- gather helpers (packed fp32, manual bf16 pack) ----
__device__ __forceinline__ void proj_pt(
    const f32x2 Px, const f32x2 Py, const f32x2 Pz, const f32x2 Pw, const f32x4 Pc,
    float px, float py, float pz,
    int& eoff, float& wx, float& wy, unsigned& gpk)
{
    f32x2 c01 = Pz*pz + Pw;          // v_pk_fma_f32
    c01 = Py*py + c01;
    c01 = Px*px + c01;
    float c2 = fmaf(Pc.x,px, fmaf(Pc.y,py, fmaf(Pc.z,pz, Pc.w)));
    float rz = __builtin_amdgcn_rcpf(c2);
    f32x2 t01 = c01*1.0254f + 0.5f*c2;
    t01 = t01*rz;
    float cx = fminf(fmaxf(t01.x, 0.f), 1.f);
    float cy = fminf(fmaxf(t01.y, 0.f), 1.f);
    float gx = fmaf(2.f, cx, -1.f);
    float gy = fmaf(2.f, cy, -1.f);
    float ixp = fmaf(64.f, cx, 0.5f);    // x0 in [0,64]
    float iyp = fmaf(64.f, cy, 0.5f);    // y0 in [0,64]
    float xf = floorf(ixp), yf = floorf(iyp);
    wx = ixp - xf; wy = iyp - yf;
    eoff = (int)yf*ST_XS + (int)xf;
    gpk = bf16pk(gx, gy);
}

// r0 = row y0 pair [e00 | e01], r1 = row y0+1 pair [e10 | e11]
__device__ __forceinline__ void bilerp_pack(
    const uint4 r0, const uint4 r1, float wx, float wy, unsigned gpk, uint4& av)
{
    float wy0 = 1.f - wy, wy1 = wy;
    float w0x = 1.f - wx, w1x = wx;
    f32x2 tl01 = unpk2(r0.x)*wy0 + unpk2(r1.x)*wy1;   // ch0,ch1 left col (pk)
    float tl2  = fmaf(wy0, bflo(r0.y), wy1*bflo(r1.y));
    f32x2 tr01 = unpk2(r0.z)*wy0 + unpk2(r1.z)*wy1;   // ch0,ch1 right col (pk)
    float tr2  = fmaf(wy0, bflo(r0.w), wy1*bflo(r1.w));
    f32x2 f01 = tl01*w0x + tr01*w1x;
    float f2  = fmaf(w0x, tl2, w1x*tr2);
    av.x = bf16pk(f01.x, f01.y);                    // [f0, f1]
    av.y = ((unsigned)bf16rne(f2)) | (gpk << 16);   // [f2, gx]
    av.z = gpk >> 16;                               // [gy, 0]
    av.w = 0u;
}

// ---- kernel 2: FUSED [imp +] gather + MFMA MLP; 512 thr; LDS weights ----
// LDS diet: imp/posl scratch UNIONED with per-wave h-transpose scratch (temporally
// separated by barriers); layer-2 weights read direct from global (coalesced, L2).
// 51.5 KB/block -> 3 blocks/CU (24 waves/CU).
__global__ __launch_bounds__(512, 6) void k_fused(
    const uint4* __restrict__ stq, const float* __restrict__ poses,
    const float* __restrict__ b1, const unsigned short* __restrict__ w1e,
    const unsigned short* __restrict__ w2e, const float* __restrict__ b2e,
    unsigned short* __restrict__ colors, float* __restrict__ dens,
    const float* __restrict__ noise, const float* __restrict__ ro,
    const float* __restrict__ rd, const float* __restrict__ u,
    float* __restrict__ ws, int coarse)
{
    __shared__ __align__(16) unsigned short w1s[16384];      // 32 KB, [chunk][lane][8]
    __shared__ __align__(16) float uni[4608];                // 18 KB union scratch
    __shared__ __align__(16) float pl[384];
    // union views (fine pre-phase): posl[6][48] float4 | impz[6][48] | impcdf[6][46]
    float4* posl  = (float4*)uni;            // 1152 floats
    float*  impz  = uni + 1152;              // 288 floats
    float*  impcdf= uni + 1440;              // 276 floats -> ends 1716 < 4608
    int tid = threadIdx.x;
    int wv = tid >> 6, lane = tid & 63;
    int n = lane & 15, q = lane >> 4;
    int bid = blockIdx.x;
    int swz = (bid & 7)*(NBLK_FUSED/8) + (bid >> 3);        // bijective, 1536 % 8 == 0
    int wlocal = swz*256 + wv*32;
    int bq = (swz*256 >= NPTS/2) ? 32 : 0;  // batch plane-base; 256-pt blocks never straddle
    int r0 = (int)(((unsigned)(swz*16) * 43691u) >> 17);    // block's first ray = swz*256/48

    {   // stage layer-1 weights + poses (coalesced, once per block)
        const uint4* g1 = (const uint4*)w1e;
        uint4* d1 = (uint4*)w1s;
        for (int i = tid; i < 2048; i += 512) d1[i] = g1[i];
        if (tid < 384) pl[tid] = poses[tid];
    }

    if (!coarse && wv < 6) {
        // importance sampling for ray r (verbatim k_imp body; wave-local LDS)
        int r = r0 + wv;                        // <= 8191 always
        const float* z   = ws + OFF_DC + (size_t)r*48;
        const float* den = ws + OFF_SC + (size_t)r*48;
        float zv = 0.f, dv = 0.f;
        if (lane < 48) { zv = z[lane]; dv = den[lane]; impz[wv*48 + lane] = zv; }
        float zn  = __shfl_down(zv, 1);
        float dnn = __shfl_down(dv, 1);
        float alpha = 0.f, f = 1.f;
        if (lane < 47) {
            float sp = softplus_f(0.5f*(dv + dnn) - 1.f);
            alpha = 1.f - __expf(-sp*(zn - zv));
            f = 1.f - alpha + 1e-10f;
        }
        float v = f;
        for (int off = 1; off < 64; off <<= 1) { float o = __shfl_up(v, off); if (lane >= off) v *= o; }
        float T = __shfl_up(v, 1); if (lane == 0) T = 1.f;
        float w = alpha*T;
        float wn1 = __shfl_down(w, 1), wn2 = __shfl_down(w, 2);
        float pw = 0.f;
        if (lane < 45) pw = 0.5f*(fmaxf(w, wn1) + fmaxf(wn1, wn2)) + 0.01f + 1e-5f;
        float s = pw;
        for (int off = 1; off < 64; off <<= 1) { float o = __shfl_up(s, off); if (lane >= off) s += o; }
        float csum = __shfl(s, 63);
        if (lane < 45) impcdf[wv*46 + lane+1] = s/csum;
        if (lane == 63) impcdf[wv*46] = 0.f;
        // wave-local LDS write->read: compiler-inserted lgkmcnt, lockstep wave
        if (lane < 48) {
            float uu = u[(size_t)r*48 + lane];
            int lo = 0, hi = 46;
            while (lo < hi) { int mid = (lo+hi)>>1; if (uu >= impcdf[wv*46 + mid]) lo = mid+1; else hi = mid; }
            int below = max(lo-1, 0), above = min(lo, 45);
            float cb = impcdf[wv*46 + below], ca = impcdf[wv*46 + above];
            float zb = impz[wv*48 + below],   za = impz[wv*48 + above];
            float dn2 = ca - cb; if (dn2 < 1e-5f) dn2 = 1.f;
            float df_s = zb + (uu - cb)/dn2*(za - zb);
            ws[OFF_DF + (size_t)r*48 + lane] = df_s;
            float fx = fmaf(df_s, rd[r*3+0], ro[r*3+0]);
            float fy = fmaf(df_s, rd[r*3+1], ro[r*3+1]);
            float fz = fmaf(df_s, rd[r*3+2], ro[r*3+2]);
            posl[wv*48 + lane] = make_float4(fx, fy, fz, df_s);
        }
    }
    __syncthreads();

    float px[2], py[2], pz[2];
    if (coarse) {
#pragma unroll
        for (int t = 0; t < 2; t++) {
            int pt = wlocal + t*16 + n;
            int ray = div48(pt);
            int j = pt - ray*48;
            float depth = 0.5f + (float)j*DELTA_ + noise[pt]*DELTA_;
            px[t] = fmaf(depth, rd[ray*3+0], ro[ray*3+0]);
            py[t] = fmaf(depth, rd[ray*3+1], ro[ray*3+1]);
            pz[t] = fmaf(depth, rd[ray*3+2], ro[ray*3+2]);
            if (q == 0) ws[OFF_DC + pt] = depth;
        }
    } else {
#pragma unroll
        for (int t = 0; t < 2; t++) {
            int pt = wlocal + t*16 + n;
            int ray = div48(pt);
            float4 pv = posl[(ray - r0)*48 + (pt - ray*48)];
            px[t] = pv.x; py[t] = pv.y; pz[t] = pv.z;
        }
    }
    __syncthreads();   // posl reads complete before any wave's epilogue reuses uni

    f32x4 acc[2][4];
#pragma unroll
    for (int t = 0; t < 2; t++)
#pragma unroll
        for (int nt = 0; nt < 4; nt++) {
            float bv = b1[nt*16 + n];
            acc[t][nt] = (f32x4){bv, bv, bv, bv};
        }

#pragma unroll
    for (int s = 0; s < 8; s++) {
        int plane = s*4 + q;
        const float* Pp = pl + plane*12;
        f32x2 Px = *(const f32x2*)(Pp);
        f32x2 Py = *(const f32x2*)(Pp + 2);
        f32x2 Pz = *(const f32x2*)(Pp + 4);
        f32x2 Pw = *(const f32x2*)(Pp + 6);
        f32x4 Pc = *(const f32x4*)(Pp + 8);
        const uint4* stp = stq + (unsigned)(bq + plane)*(unsigned)ST_PLANE;
        union { short8 s8; uint4 u; } av[2];
        {   // 4 aligned 16B loads in flight before any bilerp
            int eo0, eo1; float wx0, wy0, wx1, wy1; unsigned g0, g1;
            proj_pt(Px, Py, Pz, Pw, Pc, px[0], py[0], pz[0], eo0, wx0, wy0, g0);
            proj_pt(Px, Py, Pz, Pw, Pc, px[1], py[1], pz[1], eo1, wx1, wy1, g1);
            uint4 a0 = stp[eo0], a1 = stp[eo0 + ST_XS];
            uint4 b0 = stp[eo1], b1r = stp[eo1 + ST_XS];
            bilerp_pack(a0, a1, wx0, wy0, g0, av[0].u);
            bilerp_pack(b0, b1r, wx1, wy1, g1, av[1].u);
        }
#pragma unroll
        for (int nt = 0; nt < 4; nt++) {
            // conflict-free ds_read_b128: chunk*1KB + lane*16B
            short8 bfw = *(const short8*)(w1s + ((s*4 + nt) << 9) + (lane << 3));
#pragma unroll
            for (int t = 0; t < 2; t++)
                acc[t][nt] = __builtin_amdgcn_mfma_f32_16x16x32_bf16(av[t].s8, bfw, acc[t][nt], 0, 0, 0);
        }
    }

    // layer-2 weights: direct from global (coalesced 16B/lane, L2-resident, once/wave)
    short8 b2f[3][2];
#pragma unroll
    for (int nt = 0; nt < 3; nt++)
#pragma unroll
        for (int s2 = 0; s2 < 2; s2++)
            b2f[nt][s2] = *(const short8*)(w2e + (((nt << 1) | s2) << 9) + (lane << 3));

    unsigned short* ht = (unsigned short*)uni + wv*1152;     // per-wave 16x72 shorts
#pragma unroll
    for (int t = 0; t < 2; t++) {
        // h-tile (16 pts) -> LDS (bf16), wave-local transpose
#pragma unroll
        for (int nt = 0; nt < 4; nt++)
#pragma unroll
            for (int r = 0; r < 4; r++) {
                float hv = softplus_f(acc[t][nt][r]);
                ht[(q*4 + r)*72 + nt*16 + n] = bf16rne(hv);
            }
        short8 a2[2];
#pragma unroll
        for (int s2 = 0; s2 < 2; s2++)
            a2[s2] = *(const short8*)(ht + n*72 + s2*32 + q*8);
        // no __syncthreads: aliasing is wave-local; DS pipe in-order per wave

        f32x4 acc2[3];
#pragma unroll
        for (int nt = 0; nt < 3; nt++) {
            float bv = b2e[nt*16 + n];
            acc2[nt] = (f32x4){bv, bv, bv, bv};
        }
#pragma unroll
        for (int nt = 0; nt < 3; nt++)
#pragma unroll
            for (int s2 = 0; s2 < 2; s2++)
                acc2[nt] = __builtin_amdgcn_mfma_f32_16x16x32_bf16(a2[s2], b2f[nt][s2], acc2[nt], 0, 0, 0);

        float* ot = (float*)ht;                      // reuse same wave-local region
#pragma unroll
        for (int nt = 0; nt < 3; nt++) {
            int col = nt*16 + n;
#pragma unroll
            for (int r = 0; r < 4; r++) {
                float v = acc2[nt][r];
                int row = q*4 + r;
                if (col == 0) ot[row*34 + 32] = v;
                else if (col <= 32) {
                    float sg = sigmoid_f(v);
                    ot[row*34 + (col-1)] = fmaf(sg, 1.002f, -0.001f);
                }
            }
        }
        unsigned* cgu = (unsigned*)(colors + (size_t)(wlocal + t*16)*32);
#pragma unroll
        for (int i = 0; i < 4; i++) {
            int ui = i*64 + lane;
            int pt = ui >> 4, ch = (ui & 15)*2;
            cgu[ui] = bf16pk(ot[pt*34 + ch], ot[pt*34 + ch + 1]);
        }
        if (lane < 16) dens[wlocal + t*16 + lane] = ot[lane*34 + 32];
    }
}

// ---- kernel 5: fused sort + march + color accumulation (wave per ray) ----
__global__ __launch_bounds__(256) void k_final(float* __restrict__ out, const float* __restrict__ ws,
                                               const unsigned short* __restrict__ cC,
                                               const unsigned short* __restrict__ cF)
{
    __shared__ float kd[4][96];
    __shared__ float kden[4][96];
    __shared__ float sdl[4][96];
    __shared__ float sdenl[4][96];
    __shared__ int   sidxl[4][96];
    __shared__ float warr[4][96];
    __shared__ float earr[4][96];
    int tid = threadIdx.x;
    int wv = tid >> 6, lane = tid & 63;
    int r = blockIdx.x*4 + wv;
    const float* dc = ws + OFF_DC + (size_t)r*48;
    const float* df = ws + OFF_DF + (size_t)r*48;
    const float* sc = ws + OFF_SC + (size_t)r*48;
    const float* sf = ws + OFF_SF + (size_t)r*48;
    for (int i = lane; i < 96; i += 64) {
        float d, dn;
        if (i < 48) { d = dc[i]; dn = sc[i]; }
        else        { d = df[i-48]; dn = sf[i-48]; }
        kd[wv][i] = d; kden[wv][i] = dn;
    }
    __syncthreads();
    for (int i = lane; i < 96; i += 64) {
        float d = kd[wv][i];
        int rank = 0;
        for (int j = 0; j < 96; j++) {
            float dj = kd[wv][j];
            rank += (int)((dj < d) | ((dj == d) & (j < i)));
        }
        sdl[wv][rank] = d; sdenl[wv][rank] = kden[wv][i]; sidxl[wv][rank] = i;
    }
    __syncthreads();
    int i2 = 2*lane;
    float a0=0.f, f0=1.f, a1=0.f, f1=1.f, d0=0.f, d1=0.f, d2=0.f;
    if (i2 < 95) {
        d0 = sdl[wv][i2]; d1 = sdl[wv][i2+1];
        float sp = softplus_f(0.5f*(sdenl[wv][i2] + sdenl[wv][i2+1]) - 1.f);
        a0 = 1.f - __expf(-sp*(d1 - d0)); f0 = 1.f - a0 + 1e-10f;
    }
    if (i2+1 < 95) {
        d2 = sdl[wv][i2+2];
        float sp = softplus_f(0.5f*(sdenl[wv][i2+1] + sdenl[wv][i2+2]) - 1.f);
        a1 = 1.f - __expf(-sp*(d2 - d1)); f1 = 1.f - a1 + 1e-10f;
    }
    float p = f0*f1, v = p;
    for (int off = 1; off < 64; off <<= 1) { float o = __shfl_up(v, off); if (lane >= off) v *= o; }
    float excl = __shfl_up(v, 1); if (lane == 0) excl = 1.f;
    float w0 = a0*excl, w1 = a1*excl*f0;
    if (i2   < 96) warr[wv][i2]   = w0;
    if (i2+1 < 96) warr[wv][i2+1] = w1;
    float wsm = w0 + w1;
    float dsm = w0*0.5f*(d0+d1) + w1*0.5f*(d1+d2);
    for (int off = 32; off; off >>= 1) { wsm += __shfl_xor(wsm, off); dsm += __shfl_xor(dsm, off); }
    __syncthreads();
    for (int i = lane; i < 96; i += 64) {
        float wp = (i > 0)  ? warr[wv][i-1] : 0.f;
        float wc = (i < 95) ? warr[wv][i]   : 0.f;
        earr[wv][sidxl[wv][i]] = 0.5f*(wp + wc);
    }
    __syncthreads();
    int ch = lane & 31, half = lane >> 5;
    const unsigned short* cbase = (half ? cF : cC) + ((size_t)r*48)*32 + ch;
    const float* eb = &earr[wv][half*48];
    float a = 0.f;
    for (int jj = 0; jj < 48; jj++)
        a = fmaf(eb[jj], bf2f(cbase[(size_t)jj*32]), a);
    a += __shfl_xor(a, 32);
    if (lane < 32) out[(size_t)r*34 + lane] = 2.f*a - 1.f;
    if (lane == 0) {
        float gmn = ws[OFF_MINMAX];
        float gmx = ws[OFF_MINMAX + 1];
        float depth = dsm/wsm;
        if (depth != depth) depth = __builtin_inff();
        depth = fminf(fmaxf(depth, gmn), gmx);
        out[(size_t)r*34 + 32] = depth;
        out[(size_t)r*34 + 33] = wsm;
    }
}

extern "C" void kernel_launch(void* const* d_in, const int* in_sizes, int n_in,
                              void* d_out, int out_size, void* d_ws, size_t ws_size,
                              hipStream_t stream) {
    const float* planes = (const float*)d_in[0];
    const float* ro     = (const float*)d_in[1];
    const float* rd     = (const float*)d_in[2];
    const float* noise  = (const float*)d_in[3];
    const float* u      = (const float*)d_in[4];
    const float* W1     = (const float*)d_in[5];
    const float* b1     = (const float*)d_in[6];
    const float* W2     = (const float*)d_in[7];
    const float* b2     = (const float*)d_in[8];
    float* ws  = (float*)d_ws;
    float* out = (float*)d_out;
    const unsigned short* w1e = (const unsigned short*)(ws + OFF_W1E);
    const unsigned short* w2e = (const unsigned short*)(ws + OFF_W2E);
    const uint4* stq = (const uint4*)(ws + OFF_ST);
    unsigned short* cC = (unsigned short*)(ws + OFF_CC);
    unsigned short* cF = (unsigned short*)(ws + OFF_CF);

    hipLaunchKernelGGL(k_setup, dim3(SETUP_GRID), dim3(256), 0, stream,
                       ws, W1, W2, b2, planes, noise);
    hipLaunchKernelGGL(k_fused, dim3(NBLK_FUSED), dim3(512), 0, stream,
                       stq, ws + OFF_POSES, b1, w1e, w2e, ws + OFF_B2E, cC, ws + OFF_SC,
                       noise, ro, rd, u, ws, 1);
    hipLaunchKernelGGL(k_fused, dim3(NBLK_FUSED), dim3(512), 0, stream,
                       stq, ws + OFF_POSES, b1, w1e, w2e, ws + OFF_B2E, cF, ws + OFF_SF,
                       noise, ro, rd, u, ws, 0);
    hipLaunchKernelGGL(k_final, dim3(NRAYS/4), dim3(256), 0, stream, out, ws, cC, cF);
}

// Round 15
// 223.281 us; speedup vs baseline: 1.0238x; 1.0238x over previous
//
#include <hip/hip_runtime.h>
#include <math.h>

#define B_   2
#define N_   4096
#define S_   48
#define NPL  32
#define NRAYS (B_*N_)          // 8192
#define NPTS  (NRAYS*S_)       // 393216
#define DELTA_ (2.0f/47.0f)
#define NBLK_FUSED (NPTS/256)  // 1536 (512 thr: 8 waves x 32 pts = 256 pts/block)

// x-pair texel table: entry (plane, y, x) = texels (y,x),(y,x+1), 3ch bf16 each, 16B aligned.
#define ST_XS    65                     // x0 in [0,64]
#define ST_YS    66                     // y in [0,65]
#define ST_PLANE (ST_YS*ST_XS)          // 4290 uint4 entries per plane
#define SETUP_GRID 258                  // poses+weights + minmax + 64 planes x 4 parts

// ---- workspace layout (float offsets) ----
#define OFF_POSES  0                    // 384 (pk layout: [ax,bx,ay,by,az,bz,aw,bw,c0..c3] per plane)
#define OFF_MINMAX 384                  // 2 floats (gmin, gmax)
#define OFF_W1E    512                  // 64*256 bf16 (wave-layout [chunk][lane][8])
#define OFF_W2E    8704                 // 6*512 bf16 (wave-layout)
#define OFF_B2E    10240                // 48 floats
#define OFF_ST     16384                // table: 64*4290 uint4 = 1098240 floats -> ends 1114624
#define OFF_DC     1114624              // depths_c [NPTS]
#define OFF_DF     1507840
#define OFF_SC     1901056
#define OFF_SF     2294272
#define OFF_CC     2687488              // colors_c bf16 [NPTS*32] -> ends 8978944
#define OFF_CF     8978944              // colors_f bf16 -> ends 15270400

typedef __attribute__((ext_vector_type(8))) short short8;
typedef __attribute__((ext_vector_type(4))) float f32x4;
typedef __attribute__((ext_vector_type(2))) float f32x2;

__device__ __forceinline__ float softplus_f(float x) {
    return fmaxf(x, 0.f) + __logf(1.f + __expf(-fabsf(x)));
}
__device__ __forceinline__ float sigmoid_f(float x) {
    return __builtin_amdgcn_rcpf(1.f + __expf(-x));
}
__device__ __forceinline__ unsigned short bf16rne(float x) {
    unsigned u = __float_as_uint(x);
    u += 0x7FFFu + ((u >> 16) & 1u);
    return (unsigned short)(u >> 16);
}
__device__ __forceinline__ unsigned bf16pk(float lo, float hi) {
    return (unsigned)bf16rne(lo) | ((unsigned)bf16rne(hi) << 16);
}
__device__ __forceinline__ float bf2f(unsigned short v) {
    return __uint_as_float(((unsigned)v) << 16);
}
__device__ __forceinline__ float bflo(unsigned u) { return __uint_as_float(u << 16); }
__device__ __forceinline__ float bfhi(unsigned u) { return __uint_as_float(u & 0xffff0000u); }
__device__ __forceinline__ f32x2 unpk2(unsigned u) { return (f32x2){bflo(u), bfhi(u)}; }
// exact n/48 for n < 393216 (n>>4 < 24576: 43691 = ceil(2^17/3))
__device__ __forceinline__ int div48(int pt) {
    return (int)(((unsigned)(pt >> 4) * 43691u) >> 17);
}

__device__ void mul3(const double* a, const double* b, double* o) {
    for (int i = 0; i < 3; i++)
        for (int j = 0; j < 3; j++) {
            double s = 0.0;
            for (int k = 0; k < 3; k++) s += a[i*3+k]*b[k*3+j];
            o[i*3+j] = s;
        }
}

// ---- kernel 0: setup (258 blocks) ----
// bid 0: poses (pk layout) + weight repack; bid 1: depth minmax;
// bid 2..257: plane repack, 4 blocks per plane.
__global__ __launch_bounds__(256) void k_setup(
    float* ws, const float* __restrict__ W1,
    const float* __restrict__ W2, const float* __restrict__ b2,
    const float* __restrict__ planes, const float* __restrict__ noise)
{
    __shared__ unsigned short texs[3][4096];    // 24 KB (repack branch)
    __shared__ float smn[4], smx[4];
    int bid = blockIdx.x;
    int t = threadIdx.x;
    if (bid == 0) {
        // poses (double math, faithful)
        if (t < 32) {
            double y = 1.0 - (t/31.0)*2.0;
            double rr = sqrt(fmax(1.0 - y*y, 0.0));
            double golden = M_PI*(sqrt(5.0) - 1.0);
            double th = golden*(double)t;
            double x = cos(th)*rr, z = sin(th)*rr;
            double phi   = atan2(z, sqrt(x*x + y*y));   // radians treated as degrees (faithful)
            double theta = atan2(y, x);
            double p  = phi/180.0*M_PI;
            double tt = theta/180.0*M_PI;
            double e  = 90.0/180.0*M_PI;
            double cp = cos(p), sp = sin(p), ct = cos(tt), st = sin(tt);
            double ce = cos(e), se = sin(e);
            double Ph[9] = {1,0,0,  0,cp,-sp,  0,sp,cp};
            double Th[9] = {ct,0,-st,  0,1,0,  st,0,ct};
            double Et[9] = {ce,se,0,  -se,ce,0,  0,0,1};
            double M3[9] = {-1,0,0,  0,0,1,  0,1,0};
            double A[9], Bm[9], R[9];
            mul3(Th, Ph, A);
            mul3(Et, A, Bm);
            mul3(M3, Bm, R);
            double radius = -1.307;
            double tv0 = radius*R[2], tv1 = radius*R[5], tv2 = radius*R[8];
            double Rf[9] = {-R[0],R[1],R[2], -R[3],R[4],R[5], -R[6],R[7],R[8]};
            float rowv[3][4];
            for (int j = 0; j < 3; j++) {
                double r0 = Rf[0*3+j], r1 = Rf[1*3+j], r2 = Rf[2*3+j];
                rowv[j][0] = (float)r0;
                rowv[j][1] = (float)r1;
                rowv[j][2] = (float)r2;
                rowv[j][3] = (float)(-(r0*tv0 + r1*tv1 + r2*tv2));
            }
            // pk layout: row0/row1 interleaved by component, then row2
            float* P = ws + OFF_POSES + t*12;
            P[0] = rowv[0][0]; P[1] = rowv[1][0];
            P[2] = rowv[0][1]; P[3] = rowv[1][1];
            P[4] = rowv[0][2]; P[5] = rowv[1][2];
            P[6] = rowv[0][3]; P[7] = rowv[1][3];
            P[8] = rowv[2][0]; P[9] = rowv[2][1]; P[10] = rowv[2][2]; P[11] = rowv[2][3];
        }
        // layer-1 weights, wave layout: o = [chunk=s*4+nt][lane=q*16+n][j]
        unsigned short* w1e = (unsigned short*)(ws + OFF_W1E);
        for (int o = t; o < 64*256; o += 256) {
            int chunk = o >> 9, lane = (o >> 3) & 63, j = o & 7;
            int s = chunk >> 2, nt = chunk & 3, q = lane >> 4, n = lane & 15;
            int nn = nt*16 + n;
            int p = s*4 + q;
            float v = 0.f;
            if (j < 3)      v = W1[(3*p+j)*64 + nn];
            else if (j < 5) v = W1[(96 + 2*p + (j-3))*64 + nn];
            w1e[o] = bf16rne(v);
        }
        // layer-2 weights, wave layout: o = [chunk=nt*2+s2][lane][j]
        unsigned short* w2e = (unsigned short*)(ws + OFF_W2E);
        for (int o = t; o < 6*512; o += 256) {
            int chunk = o >> 9, lane = (o >> 3) & 63, j = o & 7;
            int nt = chunk >> 1, s2 = chunk & 1, q = lane >> 4, n = lane & 15;
            int nn = nt*16 + n;
            int k2 = s2*32 + q*8 + j;
            float v = (nn < 33) ? W2[k2*33 + nn] : 0.f;
            w2e[o] = bf16rne(v);
        }
        for (int idx = t; idx < 48; idx += 256)
            ws[OFF_B2E + idx] = (idx < 33) ? b2[idx] : 0.f;
    } else if (bid == 1) {
        // depth minmax over noise col 0 / col 47
        float mn = 1e30f, mx = -1e30f;
        for (int r = t; r < NRAYS; r += 256) {
            float n0  = noise[(size_t)r*48];
            float n47 = noise[(size_t)r*48 + 47];
            mn = fminf(mn, 0.5f + n0*DELTA_);
            mx = fmaxf(mx, 0.5f + 47.f*DELTA_ + n47*DELTA_);
        }
        for (int off = 32; off > 0; off >>= 1) {
            mn = fminf(mn, __shfl_down(mn, off));
            mx = fmaxf(mx, __shfl_down(mx, off));
        }
        if ((t & 63) == 0) { smn[t >> 6] = mn; smx[t >> 6] = mx; }
        __syncthreads();
        if (t == 0) {
            ws[OFF_MINMAX]     = fminf(fminf(smn[0], smn[1]), fminf(smn[2], smn[3]));
            ws[OFF_MINMAX + 1] = fmaxf(fmaxf(smx[0], smx[1]), fmaxf(smx[2], smx[3]));
        }
    } else {
        // plane-staged x-pair repack: 4 blocks per plane, each writes a quarter.
        int idx = bid - 2;
        int bp = idx >> 2, part = idx & 3;        // plane 0..63, quarter 0..3
        int b = bp >> 5, p = bp & 31;
        const float* base = planes + ((size_t)b*96 + 3*p)*4096;
        for (int i = t; i < 4096; i += 256) {
            texs[0][i] = bf16rne(base[i]);
            texs[1][i] = bf16rne(base[4096 + i]);
            texs[2][i] = bf16rne(base[8192 + i]);
        }
        __syncthreads();
        uint4* qd = (uint4*)(ws + OFF_ST) + (size_t)bp*ST_PLANE;
        int e0 = part*1073, e1 = min(ST_PLANE, e0 + 1073);
        for (int e = e0 + t; e < e1; e += 256) {
            int y = e / ST_XS, x = e - y*ST_XS;   // y in [0,65], x in [0,64]
            int jy = y - 1;
            unsigned a01 = 0, a2 = 0, b01 = 0, b2v = 0;
            if (jy >= 0 && jy <= 63) {
                int jxa = x - 1, jxb = x;
                if (jxa >= 0 && jxa <= 63) {
                    int ti = jy*64 + jxa;
                    a01 = (unsigned)texs[0][ti] | ((unsigned)texs[1][ti] << 16);
                    a2  = (unsigned)texs[2][ti];
                }
                if (jxb <= 63) {
                    int ti = jy*64 + jxb;
                    b01 = (unsigned)texs[0][ti] | ((unsigned)texs[1][ti] << 16);
                    b2v = (unsigned)texs[2][ti];
                }
            }
            qd[e] = make_uint4(a01, a2, b01, b2v);
        }
    }
}

// ---- gather helpers (packed fp32, manual bf16 pack) ----
__device__ __forceinline__ void proj_pt(
    const f32x2 Px, const f32x2 Py, const f32x2 Pz, const f32x2 Pw, const f32x4 Pc,
    float px, float py, float pz,
    int& eoff, float& wx, float& wy, unsigned& gpk)
{
    f32x2 c01 = Pz*pz + Pw;          // v_pk_fma_f32
    c01 = Py*py + c01;
    c01 = Px*px + c01;
    float c2 = fmaf(Pc.x,px, fmaf(Pc.y,py, fmaf(Pc.z,pz, Pc.w)));
    float rz = __builtin_amdgcn_rcpf(c2);
    f32x2 t01 = c01*1.0254f + 0.5f*c2;
    t01 = t01*rz;
    float cx = fminf(fmaxf(t01.x, 0.f), 1.f);
    float cy = fminf(fmaxf(t01.y, 0.f), 1.f);
    float gx = fmaf(2.f, cx, -1.f);
    float gy = fmaf(2.f, cy, -1.f);
    float ixp = fmaf(64.f, cx, 0.5f);    // x0 in [0,64]
    float iyp = fmaf(64.f, cy, 0.5f);    // y0 in [0,64]
    float xf = floorf(ixp), yf = floorf(iyp);
    wx = ixp - xf; wy = iyp - yf;
    eoff = (int)yf*ST_XS + (int)xf;
    gpk = bf16pk(gx, gy);
}

// r0 = row y0 pair [e00 | e01], r1 = row y0+1 pair [e10 | e11]
__device__ __forceinline__ void bilerp_pack(
    const uint4 r0, const uint4 r1, float wx, float wy, unsigned gpk, uint4& av)
{
    float wy0 = 1.f - wy, wy1 = wy;
    float w0x = 1.f - wx, w1x = wx;
    f32x2 tl01 = unpk2(r0.x)*wy0 + unpk2(r1.x)*wy1;   // ch0,ch1 left col (pk)
    float tl2  = fmaf(wy0, bflo(r0.y), wy1*bflo(r1.y));
    f32x2 tr01 = unpk2(r0.z)*wy0 + unpk2(r1.z)*wy1;   // ch0,ch1 right col (pk)
    float tr2  = fmaf(wy0, bflo(r0.w), wy1*bflo(r1.w));
    f32x2 f01 = tl01*w0x + tr01*w1x;
    float f2  = fmaf(w0x, tl2, w1x*tr2);
    av.x = bf16pk(f01.x, f01.y);                    // [f0, f1]
    av.y = ((unsigned)bf16rne(f2)) | (gpk << 16);   // [f2, gx]
    av.z = gpk >> 16;                               // [gy, 0]
    av.w = 0u;
}

// ---- kernel 2: FUSED [imp +] gather + MFMA MLP; 512 thr; LDS weights ----
// coarse=1: points from noise/ro/rd, write depths_c.
// coarse=0: waves 0..5 run importance sampling for rays r0..r0+5 (duplicates across
//           blocks write identical DF values - benign), fine positions via LDS.
__global__ __launch_bounds__(512, 4) void k_fused(
    const uint4* __restrict__ stq, const float* __restrict__ poses,
    const float* __restrict__ b1, const unsigned short* __restrict__ w1e,
    const unsigned short* __restrict__ w2e, const float* __restrict__ b2e,
    unsigned short* __restrict__ colors, float* __restrict__ dens,
    const float* __restrict__ noise, const float* __restrict__ ro,
    const float* __restrict__ rd, const float* __restrict__ u,
    float* __restrict__ ws, int coarse)
{
    __shared__ __align__(16) unsigned short w1s[16384];      // 32 KB, [chunk][lane][8]
    __shared__ __align__(16) unsigned short w2s[3072];       // 6 KB
    __shared__ __align__(16) unsigned short smem[8][1152];   // per-wave 16x72 shorts
    __shared__ __align__(16) float pl[384];
    __shared__ float impz[6][48];
    __shared__ float impcdf[6][46];
    __shared__ __align__(16) float4 posl[6][48];             // fine positions (block rays)
    int tid = threadIdx.x;
    int wv = tid >> 6, lane = tid & 63;
    int n = lane & 15, q = lane >> 4;
    int bid = blockIdx.x;
    int swz = (bid & 7)*(NBLK_FUSED/8) + (bid >> 3);        // bijective, 1536 % 8 == 0
    int wlocal = swz*256 + wv*32;
    int bq = (swz*256 >= NPTS/2) ? 32 : 0;  // batch plane-base; 256-pt blocks never straddle
    int r0 = (int)(((unsigned)(swz*16) * 43691u) >> 17);    // block's first ray = swz*256/48

    {   // stage weights + poses (coalesced, once per block)
        const uint4* g1 = (const uint4*)w1e;
        uint4* d1 = (uint4*)w1s;
        for (int i = tid; i < 2048; i += 512) d1[i] = g1[i];
        const uint4* g2 = (const uint4*)w2e;
        uint4* d2 = (uint4*)w2s;
        if (tid < 384) { d2[tid] = g2[tid]; pl[tid] = poses[tid]; }
    }

    if (!coarse && wv < 6) {
        // importance sampling for ray r (verbatim k_imp body; wave-local LDS)
        int r = r0 + wv;                        // <= 8191 always
        const float* z   = ws + OFF_DC + (size_t)r*48;
        const float* den = ws + OFF_SC + (size_t)r*48;
        float zv = 0.f, dv = 0.f;
        if (lane < 48) { zv = z[lane]; dv = den[lane]; impz[wv][lane] = zv; }
        float zn  = __shfl_down(zv, 1);
        float dnn = __shfl_down(dv, 1);
        float alpha = 0.f, f = 1.f;
        if (lane < 47) {
            float sp = softplus_f(0.5f*(dv + dnn) - 1.f);
            alpha = 1.f - __expf(-sp*(zn - zv));
            f = 1.f - alpha + 1e-10f;
        }
        float v = f;
        for (int off = 1; off < 64; off <<= 1) { float o = __shfl_up(v, off); if (lane >= off) v *= o; }
        float T = __shfl_up(v, 1); if (lane == 0) T = 1.f;
        float w = alpha*T;
        float wn1 = __shfl_down(w, 1), wn2 = __shfl_down(w, 2);
        float pw = 0.f;
        if (lane < 45) pw = 0.5f*(fmaxf(w, wn1) + fmaxf(wn1, wn2)) + 0.01f + 1e-5f;
        float s = pw;
        for (int off = 1; off < 64; off <<= 1) { float o = __shfl_up(s, off); if (lane >= off) s += o; }
        float csum = __shfl(s, 63);
        if (lane < 45) impcdf[wv][lane+1] = s/csum;
        if (lane == 63) impcdf[wv][0] = 0.f;
        // wave-local LDS write->read: compiler-inserted lgkmcnt, lockstep wave
        if (lane < 48) {
            float uu = u[(size_t)r*48 + lane];
            int lo = 0, hi = 46;
            while (lo < hi) { int mid = (lo+hi)>>1; if (uu >= impcdf[wv][mid]) lo = mid+1; else hi = mid; }
            int below = max(lo-1, 0), above = min(lo, 45);
            float cb = impcdf[wv][below], ca = impcdf[wv][above];
            float zb = impz[wv][below],   za = impz[wv][above];
            float dn2 = ca - cb; if (dn2 < 1e-5f) dn2 = 1.f;
            float df_s = zb + (uu - cb)/dn2*(za - zb);
            ws[OFF_DF + (size_t)r*48 + lane] = df_s;
            float fx = fmaf(df_s, rd[r*3+0], ro[r*3+0]);
            float fy = fmaf(df_s, rd[r*3+1], ro[r*3+1]);
            float fz = fmaf(df_s, rd[r*3+2], ro[r*3+2]);
            posl[wv][lane] = make_float4(fx, fy, fz, df_s);
        }
    }
    __syncthreads();

    float px[2], py[2], pz[2];
    if (coarse) {
#pragma unroll
        for (int t = 0; t < 2; t++) {
            int pt = wlocal + t*16 + n;
            int ray = div48(pt);
            int j = pt - ray*48;
            float depth = 0.5f + (float)j*DELTA_ + noise[pt]*DELTA_;
            px[t] = fmaf(depth, rd[ray*3+0], ro[ray*3+0]);
            py[t] = fmaf(depth, rd[ray*3+1], ro[ray*3+1]);
            pz[t] = fmaf(depth, rd[ray*3+2], ro[ray*3+2]);
            if (q == 0) ws[OFF_DC + pt] = depth;
        }
    } else {
#pragma unroll
        for (int t = 0; t < 2; t++) {
            int pt = wlocal + t*16 + n;
            int ray = div48(pt);
            float4 pv = posl[ray - r0][pt - ray*48];
            px[t] = pv.x; py[t] = pv.y; pz[t] = pv.z;
        }
    }

    f32x4 acc[2][4];
#pragma unroll
    for (int t = 0; t < 2; t++)
#pragma unroll
        for (int nt = 0; nt < 4; nt++) {
            float bv = b1[nt*16 + n];
            acc[t][nt] = (f32x4){bv, bv, bv, bv};
        }

#pragma unroll
    for (int s = 0; s < 8; s++) {
        int plane = s*4 + q;
        const float* Pp = pl + plane*12;
        f32x2 Px = *(const f32x2*)(Pp);
        f32x2 Py = *(const f32x2*)(Pp + 2);
        f32x2 Pz = *(const f32x2*)(Pp + 4);
        f32x2 Pw = *(const f32x2*)(Pp + 6);
        f32x4 Pc = *(const f32x4*)(Pp + 8);
        const uint4* stp = stq + (unsigned)(bq + plane)*(unsigned)ST_PLANE;
        union { short8 s8; uint4 u; } av[2];
        {   // 4 aligned 16B loads in flight before any bilerp
            int eo0, eo1; float wx0, wy0, wx1, wy1; unsigned g0, g1;
            proj_pt(Px, Py, Pz, Pw, Pc, px[0], py[0], pz[0], eo0, wx0, wy0, g0);
            proj_pt(Px, Py, Pz, Pw, Pc, px[1], py[1], pz[1], eo1, wx1, wy1, g1);
            uint4 a0 = stp[eo0], a1 = stp[eo0 + ST_XS];
            uint4 b0 = stp[eo1], b1r = stp[eo1 + ST_XS];
            bilerp_pack(a0, a1, wx0, wy0, g0, av[0].u);
            bilerp_pack(b0, b1r, wx1, wy1, g1, av[1].u);
        }
#pragma unroll
        for (int nt = 0; nt < 4; nt++) {
            // conflict-free ds_read_b128: chunk*1KB + lane*16B
            short8 bfw = *(const short8*)(w1s + ((s*4 + nt) << 9) + (lane << 3));
#pragma unroll
            for (int t = 0; t < 2; t++)
                acc[t][nt] = __builtin_amdgcn_mfma_f32_16x16x32_bf16(av[t].s8, bfw, acc[t][nt], 0, 0, 0);
        }
    }

    // layer-2 weights (from LDS, shared across t-tiles)
    short8 b2f[3][2];
#pragma unroll
    for (int nt = 0; nt < 3; nt++)
#pragma unroll
        for (int s2 = 0; s2 < 2; s2++)
            b2f[nt][s2] = *(const short8*)(w2s + (((nt << 1) | s2) << 9) + (lane << 3));

    unsigned short* ht = &smem[wv][0];
#pragma unroll
    for (int t = 0; t < 2; t++) {
        // h-tile (16 pts) -> LDS (bf16), wave-local transpose
#pragma unroll
        for (int nt = 0; nt < 4; nt++)
#pragma unroll
            for (int r = 0; r < 4; r++) {
                float hv = softplus_f(acc[t][nt][r]);
                ht[(q*4 + r)*72 + nt*16 + n] = bf16rne(hv);
            }
        short8 a2[2];
#pragma unroll
        for (int s2 = 0; s2 < 2; s2++)
            a2[s2] = *(const short8*)(ht + n*72 + s2*32 + q*8);
        // no __syncthreads: aliasing is wave-local; DS pipe in-order per wave

        f32x4 acc2[3];
#pragma unroll
        for (int nt = 0; nt < 3; nt++) {
            float bv = b2e[nt*16 + n];
            acc2[nt] = (f32x4){bv, bv, bv, bv};
        }
#pragma unroll
        for (int nt = 0; nt < 3; nt++)
#pragma unroll
            for (int s2 = 0; s2 < 2; s2++)
                acc2[nt] = __builtin_amdgcn_mfma_f32_16x16x32_bf16(a2[s2], b2f[nt][s2], acc2[nt], 0, 0, 0);

        float* ot = (float*)ht;                      // reuse same wave-local region
#pragma unroll
        for (int nt = 0; nt < 3; nt++) {
            int col = nt*16 + n;
#pragma unroll
            for (int r = 0; r < 4; r++) {
                float v = acc2[nt][r];
                int row = q*4 + r;
                if (col == 0) ot[row*34 + 32] = v;
                else if (col <= 32) {
                    float sg = sigmoid_f(v);
                    ot[row*34 + (col-1)] = fmaf(sg, 1.002f, -0.001f);
                }
            }
        }
        unsigned* cgu = (unsigned*)(colors + (size_t)(wlocal + t*16)*32);
#pragma unroll
        for (int i = 0; i < 4; i++) {
            int ui = i*64 + lane;
            int pt = ui >> 4, ch = (ui & 15)*2;
            cgu[ui] = bf16pk(ot[pt*34 + ch], ot[pt*34 + ch + 1]);
        }
        if (lane < 16) dens[wlocal + t*16 + lane] = ot[lane*34 + 32];
    }
}

// ---- kernel 5: fused sort + march + color accumulation (wave per ray) ----
__global__ __launch_bounds__(256) void k_final(float* __restrict__ out, const float* __restrict__ ws,
                                               const unsigned short* __restrict__ cC,
                                               const unsigned short* __restrict__ cF)
{
    __shared__ float kd[4][96];
    __shared__ float kden[4][96];
    __shared__ float sdl[4][96];
    __shared__ float sdenl[4][96];
    __shared__ int   sidxl[4][96];
    __shared__ float warr[4][96];
    __shared__ float earr[4][96];
    int tid = threadIdx.x;
    int wv = tid >> 6, lane = tid & 63;
    int r = blockIdx.x*4 + wv;
    const float* dc = ws + OFF_DC + (size_t)r*48;
    const float* df = ws + OFF_DF + (size_t)r*48;
    const float* sc = ws + OFF_SC + (size_t)r*48;
    const float* sf = ws + OFF_SF + (size_t)r*48;
    for (int i = lane; i < 96; i += 64) {
        float d, dn;
        if (i < 48) { d = dc[i]; dn = sc[i]; }
        else        { d = df[i-48]; dn = sf[i-48]; }
        kd[wv][i] = d; kden[wv][i] = dn;
    }
    __syncthreads();
    for (int i = lane; i < 96; i += 64) {
        float d = kd[wv][i];
        int rank = 0;
        for (int j = 0; j < 96; j++) {
            float dj = kd[wv][j];
            rank += (int)((dj < d) | ((dj == d) & (j < i)));
        }
        sdl[wv][rank] = d; sdenl[wv][rank] = kden[wv][i]; sidxl[wv][rank] = i;
    }
    __syncthreads();
    int i2 = 2*lane;
    float a0=0.f, f0=1.f, a1=0.f, f1=1.f, d0=0.f, d1=0.f, d2=0.f;
    if (i2 < 95) {
        d0 = sdl[wv][i2]; d1 = sdl[wv][i2+1];
        float sp = softplus_f(0.5f*(sdenl[wv][i2] + sdenl[wv][i2+1]) - 1.f);
        a0 = 1.f - __expf(-sp*(d1 - d0)); f0 = 1.f - a0 + 1e-10f;
    }
    if (i2+1 < 95) {
        d2 = sdl[wv][i2+2];
        float sp = softplus_f(0.5f*(sdenl[wv][i2+1] + sdenl[wv][i2+2]) - 1.f);
        a1 = 1.f - __expf(-sp*(d2 - d1)); f1 = 1.f - a1 + 1e-10f;
    }
    float p = f0*f1, v = p;
    for (int off = 1; off < 64; off <<= 1) { float o = __shfl_up(v, off); if (lane >= off) v *= o; }
    float excl = __shfl_up(v, 1); if (lane == 0) excl = 1.f;
    float w0 = a0*excl, w1 = a1*excl*f0;
    if (i2   < 96) warr[wv][i2]   = w0;
    if (i2+1 < 96) warr[wv][i2+1] = w1;
    float wsm = w0 + w1;
    float dsm = w0*0.5f*(d0+d1) + w1*0.5f*(d1+d2);
    for (int off = 32; off; off >>= 1) { wsm += __shfl_xor(wsm, off); dsm += __shfl_xor(dsm, off); }
    __syncthreads();
    for (int i = lane; i < 96; i += 64) {
        float wp = (i > 0)  ? warr[wv][i-1] : 0.f;
        float wc = (i < 95) ? warr[wv][i]   : 0.f;
        earr[wv][sidxl[wv][i]] = 0.5f*(wp + wc);
    }
    __syncthreads();
    int ch = lane & 31, half = lane >> 5;
    const unsigned short* cbase = (half ? cF : cC) + ((size_t)r*48)*32 + ch;
    const float* eb = &earr[wv][half*48];
    float a = 0.f;
    for (int jj = 0; jj < 48; jj++)
        a = fmaf(eb[jj], bf2f(cbase[(size_t)jj*32]), a);
    a += __shfl_xor(a, 32);
    if (lane < 32) out[(size_t)r*34 + lane] = 2.f*a - 1.f;
    if (lane == 0) {
        float gmn = ws[OFF_MINMAX];
        float gmx = ws[OFF_MINMAX + 1];
        float depth = dsm/wsm;
        if (depth != depth) depth = __builtin_inff();
        depth = fminf(fmaxf(depth, gmn), gmx);
        out[(size_t)r*34 + 32] = depth;
        out[(size_t)r*34 + 33] = wsm;
    }
}

extern "C" void kernel_launch(void* const* d_in, const int* in_sizes, int n_in,
                              void* d_out, int out_size, void* d_ws, size_t ws_size,
                              hipStream_t stream) {
    const float* planes = (const float*)d_in[0];
    const float* ro     = (const float*)d_in[1];
    const float* rd     = (const float*)d_in[2];
    const float* noise  = (const float*)d_in[3];
    const float* u      = (const float*)d_in[4];
    const float* W1     = (const float*)d_in[5];
    const float* b1     = (const float*)d_in[6];
    const float* W2     = (const float*)d_in[7];
    const float* b2     = (const float*)d_in[8];
    float* ws  = (float*)d_ws;
    float* out = (float*)d_out;
    const unsigned short* w1e = (const unsigned short*)(ws + OFF_W1E);
    const unsigned short* w2e = (const unsigned short*)(ws + OFF_W2E);
    const uint4* stq = (const uint4*)(ws + OFF_ST);
    unsigned short* cC = (unsigned short*)(ws + OFF_CC);
    unsigned short* cF = (unsigned short*)(ws + OFF_CF);

    hipLaunchKernelGGL(k_setup, dim3(SETUP_GRID), dim3(256), 0, stream,
                       ws, W1, W2, b2, planes, noise);
    hipLaunchKernelGGL(k_fused, dim3(NBLK_FUSED), dim3(512), 0, stream,
                       stq, ws + OFF_POSES, b1, w1e, w2e, ws + OFF_B2E, cC, ws + OFF_SC,
                       noise, ro, rd, u, ws, 1);
    hipLaunchKernelGGL(k_fused, dim3(NBLK_FUSED), dim3(512), 0, stream,
                       stq, ws + OFF_POSES, b1, w1e, w2e, ws + OFF_B2E, cF, ws + OFF_SF,
                       noise, ro, rd, u, ws, 0);
    hipLaunchKernelGGL(k_final, dim3(NRAYS/4), dim3(256), 0, stream, out, ws, cC, cF);
}